// Round 1
// baseline (590.545 us; speedup 1.0000x reference)
//
#include <hip/hip_runtime.h>
#include <hip/hip_bf16.h>
#include <stdint.h>

// ---------------- problem constants (fixed by setup_inputs) ----------------
#define NHD   12        // heads
#define NPT   4         // points
#define CDIM  768
#define HDIM  64
#define NLVL  3
#define LQ    4096
#define NB    4
#define LIN   21504     // 128*128 + 64*64 + 32*32
#define MQ    (NB*LQ)   // 16384 query rows
#define MF    (NB*LIN)  // 86016 feat rows
#define SO_N    288
#define SO_NPAD 384
#define AW_N    144
#define AW_NPAD 256

typedef __bf16 bfx8 __attribute__((ext_vector_type(8)));
typedef float  f32x4 __attribute__((ext_vector_type(4)));

__device__ __forceinline__ ushort f2bf(float x) {
  union { float f; uint32_t u; } v; v.f = x;
  uint32_t r = v.u + 0x7fffu + ((v.u >> 16) & 1u);   // RNE
  return (ushort)(r >> 16);
}
__device__ __forceinline__ float bf2f(ushort u) {
  union { uint32_t u; float f; } v; v.u = ((uint32_t)u) << 16;
  return v.f;
}

// ---------------- weight transpose + cast:  Wt[n][k] = bf16(W[k][n]) -------
__global__ void transpose_cast(const float* __restrict__ W, ushort* __restrict__ Wt,
                               int K, int Nsrc, int Npad) {
  int t = blockIdx.x * 256 + threadIdx.x;
  if (t >= Npad * K) return;
  int n = t / K, k = t - n * K;
  Wt[t] = (n < Nsrc) ? f2bf(W[(size_t)k * Nsrc + n]) : (ushort)0;
}

__global__ void pad_bias(const float* __restrict__ src, float* __restrict__ dst,
                         int nReal, int nPad) {
  int i = blockIdx.x * 256 + threadIdx.x;
  if (i < nPad) dst[i] = (i < nReal) ? src[i] : 0.f;
}

// ---------------- LayerNorm + cast to bf16 (one block per row) -------------
__global__ __launch_bounds__(192) void ln_cast(const float* __restrict__ x,
                                               const float* __restrict__ w,
                                               const float* __restrict__ b,
                                               ushort* __restrict__ y) {
  const int row = blockIdx.x;
  const int tid = threadIdx.x;                  // 192 threads * float4 = 768
  const float4 v = ((const float4*)(x + (size_t)row * CDIM))[tid];
  float s1 = v.x + v.y + v.z + v.w;
  float s2 = v.x*v.x + v.y*v.y + v.z*v.z + v.w*v.w;
#pragma unroll
  for (int o = 32; o > 0; o >>= 1) { s1 += __shfl_down(s1, o); s2 += __shfl_down(s2, o); }
  __shared__ float r1[3], r2[3];
  const int lane = tid & 63, wv = tid >> 6;
  if (lane == 0) { r1[wv] = s1; r2[wv] = s2; }
  __syncthreads();
  s1 = r1[0] + r1[1] + r1[2];
  s2 = r2[0] + r2[1] + r2[2];
  const float mu = s1 * (1.f / CDIM);
  const float rs = rsqrtf(s2 * (1.f / CDIM) - mu * mu + 1e-6f);
  const float4 w4 = ((const float4*)w)[tid];
  const float4 b4 = ((const float4*)b)[tid];
  ushort4 o4;
  o4.x = f2bf((v.x - mu) * rs * w4.x + b4.x);
  o4.y = f2bf((v.y - mu) * rs * w4.y + b4.y);
  o4.z = f2bf((v.z - mu) * rs * w4.z + b4.z);
  o4.w = f2bf((v.w - mu) * rs * w4.w + b4.w);
  ((ushort4*)(y + (size_t)row * CDIM))[tid] = o4;
}

// ---------------- bf16 GEMM: C[M][N] = A[M][K] * Wt[N][K]^T + bias ---------
// 128x128 tile, 4 waves (2x2), 16x16x32 MFMA, BK=32, double-buffered LDS,
// global_load_lds width-16 staging (m97 structure).
// MODE 0: store bf16.  MODE 1: store f32.  MODE 2: f32, out = resid + gamma*(acc+bias)
template<int MODE>
__global__ __launch_bounds__(256) void gemm_bt(
    const ushort* __restrict__ A, const ushort* __restrict__ Wt,
    const float* __restrict__ bias, void* __restrict__ Cout,
    int M, int N, int K, int nTN,
    const float* __restrict__ resid, const float* __restrict__ gammav)
{
  const int mt = blockIdx.x / nTN;
  const int nt = blockIdx.x - mt * nTN;
  const int m0 = mt * 128, n0 = nt * 128;
  const int tid  = threadIdx.x;
  const int lane = tid & 63, wid = tid >> 6;
  const int wm = wid >> 1, wn = wid & 1;          // 2x2 wave grid, 64x64 each
  const int lr = lane & 15, lk = lane >> 4;

  __shared__ __align__(16) ushort lds[2][8192];   // per buf: A[128][32] + B[128][32]

  f32x4 acc[4][4] = {};

  auto stage = [&](int kt, int buf) {
    const int k0 = kt * 32;
#pragma unroll
    for (int it = 0; it < 2; ++it) {
      const int c   = it * 256 + wid * 64 + lane;     // 16B chunk id, 512 total
      const int row = c >> 2, g = c & 3;
      const ushort* srcA = A + (size_t)(m0 + row) * K + (k0 + g * 8);
      ushort* dstA = &lds[buf][(it * 256 + wid * 64) * 8];   // wave-uniform base
      __builtin_amdgcn_global_load_lds(
          (const __attribute__((address_space(1))) uint32_t*)srcA,
          (__attribute__((address_space(3))) uint32_t*)dstA, 16, 0, 0);
      const ushort* srcB = Wt + (size_t)(n0 + row) * K + (k0 + g * 8);
      ushort* dstB = &lds[buf][4096 + (it * 256 + wid * 64) * 8];
      __builtin_amdgcn_global_load_lds(
          (const __attribute__((address_space(1))) uint32_t*)srcB,
          (__attribute__((address_space(3))) uint32_t*)dstB, 16, 0, 0);
    }
  };

  stage(0, 0);
  __syncthreads();
  const int nk = K >> 5;
  for (int kt = 0; kt < nk; ++kt) {
    const int cur = kt & 1;
    if (kt + 1 < nk) stage(kt + 1, cur ^ 1);
    const ushort* As = &lds[cur][0];
    const ushort* Bs = &lds[cur][4096];
    bfx8 af[4], bv[4];
#pragma unroll
    for (int m = 0; m < 4; ++m)
      af[m] = *(const bfx8*)(As + (wm * 64 + m * 16 + lr) * 32 + lk * 8);
#pragma unroll
    for (int n = 0; n < 4; ++n)
      bv[n] = *(const bfx8*)(Bs + (wn * 64 + n * 16 + lr) * 32 + lk * 8);
#pragma unroll
    for (int m = 0; m < 4; ++m)
#pragma unroll
      for (int n = 0; n < 4; ++n)
        acc[m][n] = __builtin_amdgcn_mfma_f32_16x16x32_bf16(af[m], bv[n], acc[m][n], 0, 0, 0);
    __syncthreads();
  }

  // epilogue: D row = 4*(lane>>4)+i, col = lane&15  (m89-verified layout)
#pragma unroll
  for (int n = 0; n < 4; ++n) {
    const int col = n0 + wn * 64 + n * 16 + lr;
    const float bcol = bias[col];
    float gcol = 0.f;
    if constexpr (MODE == 2) gcol = gammav[col];
#pragma unroll
    for (int m = 0; m < 4; ++m) {
      const int rbase = m0 + wm * 64 + m * 16 + lk * 4;
#pragma unroll
      for (int i = 0; i < 4; ++i) {
        const size_t o = (size_t)(rbase + i) * N + col;
        const float v = acc[m][n][i] + bcol;
        if constexpr (MODE == 0)      ((ushort*)Cout)[o] = f2bf(v);
        else if constexpr (MODE == 1) ((float*)Cout)[o]  = v;
        else                          ((float*)Cout)[o]  = resid[o] + gcol * v;
      }
    }
  }
}

// ---------------- softmax over L*NP=12 per (n,q,h) --------------------------
__global__ void softmax_aw(const float* __restrict__ raw, float* __restrict__ out) {
  int t = blockIdx.x * 256 + threadIdx.x;            // [0, MQ*NHD)
  int h = t % NHD, nq = t / NHD;
  const float* p = raw + (size_t)nq * AW_NPAD + h * 12;
  float v[12], m = -1e30f;
#pragma unroll
  for (int j = 0; j < 12; ++j) { v[j] = p[j]; m = fmaxf(m, v[j]); }
  float s = 0.f;
#pragma unroll
  for (int j = 0; j < 12; ++j) { v[j] = __expf(v[j] - m); s += v[j]; }
  const float inv = 1.f / s;
  float* o = out + (size_t)nq * AW_N + h * 12;
#pragma unroll
  for (int j = 0; j < 12; ++j) o[j] = v[j] * inv;
}

// ---------------- deformable bilinear sampling ------------------------------
// one wave per (n,q,h); lane = channel d. value is [N*LIN][768] bf16.
__global__ __launch_bounds__(256) void deform_sample(
    const ushort* __restrict__ value, const float* __restrict__ off,
    const float* __restrict__ aw, const float* __restrict__ refp,
    ushort* __restrict__ samp)
{
  const int task = blockIdx.x * 4 + (threadIdx.x >> 6);
  const int lane = threadIdx.x & 63;
  const int h  = task % NHD;
  const int nq = task / NHD;
  const int n  = nq >> 12;                       // Lq = 4096
  const int Wl[3] = {128, 64, 32};
  const int STl[3] = {0, 16384, 20480};
  const float* offp = off  + (size_t)nq * SO_NPAD + h * 24;
  const float* awp  = aw   + (size_t)nq * AW_N    + h * 12;
  const float* rp   = refp + (size_t)nq * (NLVL * 2);
  float acc = 0.f;
#pragma unroll
  for (int l = 0; l < NLVL; ++l) {
    const int W_ = Wl[l], H_ = Wl[l];
    const size_t vbase = ((size_t)n * LIN + STl[l]) * CDIM + h * HDIM + lane;
    const float rx = rp[l * 2 + 0], ry = rp[l * 2 + 1];
#pragma unroll
    for (int p = 0; p < NPT; ++p) {
      const float ox = offp[(l * 4 + p) * 2 + 0];
      const float oy = offp[(l * 4 + p) * 2 + 1];
      const float a  = awp[l * 4 + p];
      const float px = rx * W_ + ox - 0.5f;      // == (rx + ox/W)*W - 0.5
      const float py = ry * H_ + oy - 0.5f;
      const float fx = floorf(px), fy = floorf(py);
      const float tx = px - fx, ty = py - fy;
      const int x0 = (int)fx, y0 = (int)fy;
#pragma unroll
      for (int c = 0; c < 4; ++c) {
        const int dx = c & 1, dy = c >> 1;
        const int xi = x0 + dx, yi = y0 + dy;
        const bool ok = (xi >= 0) & (xi < W_) & (yi >= 0) & (yi < H_);
        const float wgt = (dx ? tx : 1.f - tx) * (dy ? ty : 1.f - ty);
        const int xc = xi < 0 ? 0 : (xi > W_ - 1 ? W_ - 1 : xi);
        const int yc = yi < 0 ? 0 : (yi > H_ - 1 ? H_ - 1 : yi);
        const float g = bf2f(value[vbase + (size_t)(yc * W_ + xc) * CDIM]);
        acc += ok ? a * wgt * g : 0.f;
      }
    }
  }
  samp[(size_t)nq * CDIM + h * HDIM + lane] = f2bf(acc);
}

// ---------------- host ------------------------------------------------------
extern "C" void kernel_launch(void* const* d_in, const int* in_sizes, int n_in,
                              void* d_out, int out_size, void* d_ws, size_t ws_size,
                              hipStream_t stream) {
  const float* query = (const float*)d_in[0];
  const float* refp  = (const float*)d_in[1];
  const float* feat  = (const float*)d_in[2];
  const float* qn_w  = (const float*)d_in[3];
  const float* qn_b  = (const float*)d_in[4];
  const float* fn_w  = (const float*)d_in[5];
  const float* fn_b  = (const float*)d_in[6];
  const float* gamma = (const float*)d_in[7];
  const float* so_w  = (const float*)d_in[8];
  const float* so_b  = (const float*)d_in[9];
  const float* aw_w  = (const float*)d_in[10];
  const float* aw_b  = (const float*)d_in[11];
  const float* vp_w  = (const float*)d_in[12];
  const float* vp_b  = (const float*)d_in[13];
  const float* op_w  = (const float*)d_in[14];
  const float* op_b  = (const float*)d_in[15];

  char* ws = (char*)d_ws;
  size_t off = 0;
  auto alloc = [&](size_t bytes) {
    char* p = ws + off;
    off = (off + bytes + 255) & ~(size_t)255;
    return p;
  };
  ushort* q_bf   = (ushort*)alloc((size_t)MQ * CDIM * 2);
  ushort* val_bf = (ushort*)alloc((size_t)MF * CDIM * 2);
  ushort* vp_wT  = (ushort*)alloc((size_t)CDIM * CDIM * 2);
  ushort* op_wT  = (ushort*)alloc((size_t)CDIM * CDIM * 2);
  ushort* so_wT  = (ushort*)alloc((size_t)SO_NPAD * CDIM * 2);
  ushort* aw_wT  = (ushort*)alloc((size_t)AW_NPAD * CDIM * 2);
  float*  so_bp  = (float*)alloc(SO_NPAD * 4);
  float*  aw_bp  = (float*)alloc(AW_NPAD * 4);

  // region R: f_bf (phase A) aliases the phase-B buffers (value GEMM is the
  // last consumer of f_bf; so/aw GEMMs run strictly after it on the stream)
  const size_t r = off;
  ushort* f_bf = (ushort*)(ws + r);
  const size_t f_end = r + (size_t)MF * CDIM * 2;
  size_t o2 = r;
  float*  off_raw = (float*)(ws + o2);  o2 += (size_t)MQ * SO_NPAD * 4;
  float*  aw_raw  = (float*)(ws + o2);  o2 += (size_t)MQ * AW_NPAD * 4;
  float*  aw_sm   = (float*)(ws + o2);  o2 += (size_t)MQ * AW_N * 4;
  ushort* samp    = (ushort*)(ws + o2); o2 += (size_t)MQ * CDIM * 2;
  const size_t need = (f_end > o2) ? f_end : o2;
  if (ws_size < need) return;   // ~293 MB required

  // 1) weights -> bf16 transposed (+ padded biases)
  transpose_cast<<<(CDIM * CDIM + 255) / 256, 256, 0, stream>>>(vp_w, vp_wT, CDIM, CDIM, CDIM);
  transpose_cast<<<(CDIM * CDIM + 255) / 256, 256, 0, stream>>>(op_w, op_wT, CDIM, CDIM, CDIM);
  transpose_cast<<<(SO_NPAD * CDIM + 255) / 256, 256, 0, stream>>>(so_w, so_wT, CDIM, SO_N, SO_NPAD);
  transpose_cast<<<(AW_NPAD * CDIM + 255) / 256, 256, 0, stream>>>(aw_w, aw_wT, CDIM, AW_N, AW_NPAD);
  pad_bias<<<2, 256, 0, stream>>>(so_b, so_bp, SO_N, SO_NPAD);
  pad_bias<<<1, 256, 0, stream>>>(aw_b, aw_bp, AW_N, AW_NPAD);

  // 2) layernorms -> bf16
  ln_cast<<<MQ, 192, 0, stream>>>(query, qn_w, qn_b, q_bf);
  ln_cast<<<MF, 192, 0, stream>>>(feat, fn_w, fn_b, f_bf);

  // 3) value = LN(feat) @ vp_w + vp_b          (bf16 out)
  gemm_bt<0><<<(MF / 128) * (CDIM / 128), 256, 0, stream>>>(
      f_bf, vp_wT, vp_b, val_bf, MF, CDIM, CDIM, CDIM / 128, nullptr, nullptr);

  // 4) sampling offsets / attention weights    (f32 out, padded N)
  gemm_bt<1><<<(MQ / 128) * (SO_NPAD / 128), 256, 0, stream>>>(
      q_bf, so_wT, so_bp, off_raw, MQ, SO_NPAD, CDIM, SO_NPAD / 128, nullptr, nullptr);
  gemm_bt<1><<<(MQ / 128) * (AW_NPAD / 128), 256, 0, stream>>>(
      q_bf, aw_wT, aw_bp, aw_raw, MQ, AW_NPAD, CDIM, AW_NPAD / 128, nullptr, nullptr);

  // 5) softmax over 12
  softmax_aw<<<(MQ * NHD) / 256, 256, 0, stream>>>(aw_raw, aw_sm);

  // 6) deformable sampling -> samp bf16 [MQ][768]
  deform_sample<<<(MQ * NHD) / 4, 256, 0, stream>>>(val_bf, off_raw, aw_sm, refp, samp);

  // 7) out = query + gamma * (samp @ op_w + op_b)
  gemm_bt<2><<<(MQ / 128) * (CDIM / 128), 256, 0, stream>>>(
      samp, op_wT, op_b, (float*)d_out, MQ, CDIM, CDIM, CDIM / 128, query, gamma);
}

// Round 2
// 517.813 us; speedup vs baseline: 1.1405x; 1.1405x over previous
//
#include <hip/hip_runtime.h>
#include <hip/hip_bf16.h>
#include <stdint.h>

// ---------------- problem constants (fixed by setup_inputs) ----------------
#define NHD   12        // heads
#define NPT   4         // points
#define CDIM  768
#define HDIM  64
#define NLVL  3
#define LQ    4096
#define NB    4
#define LIN   21504     // 128*128 + 64*64 + 32*32
#define MQ    (NB*LQ)   // 16384 query rows
#define MF    (NB*LIN)  // 86016 feat rows
#define SO_N    288
#define SO_NPAD 384
#define AW_N    144
#define AW_NPAD 256

typedef __bf16 bfx8 __attribute__((ext_vector_type(8)));
typedef float  f32x4 __attribute__((ext_vector_type(4)));

__device__ __forceinline__ ushort f2bf(float x) {
  union { float f; uint32_t u; } v; v.f = x;
  uint32_t r = v.u + 0x7fffu + ((v.u >> 16) & 1u);   // RNE
  return (ushort)(r >> 16);
}

// ---------------- weight transpose + cast:  Wt[n][k] = bf16(W[k][n]) -------
__global__ void transpose_cast(const float* __restrict__ W, ushort* __restrict__ Wt,
                               int K, int Nsrc, int Npad) {
  int t = blockIdx.x * 256 + threadIdx.x;
  if (t >= Npad * K) return;
  int n = t / K, k = t - n * K;
  Wt[t] = (n < Nsrc) ? f2bf(W[(size_t)k * Nsrc + n]) : (ushort)0;
}

__global__ void pad_bias(const float* __restrict__ src, float* __restrict__ dst,
                         int nReal, int nPad) {
  int i = blockIdx.x * 256 + threadIdx.x;
  if (i < nPad) dst[i] = (i < nReal) ? src[i] : 0.f;
}

// ---------------- LayerNorm + cast to bf16 (one block per row) -------------
__global__ __launch_bounds__(192) void ln_cast(const float* __restrict__ x,
                                               const float* __restrict__ w,
                                               const float* __restrict__ b,
                                               ushort* __restrict__ y) {
  const int row = blockIdx.x;
  const int tid = threadIdx.x;                  // 192 threads * float4 = 768
  const float4 v = ((const float4*)(x + (size_t)row * CDIM))[tid];
  float s1 = v.x + v.y + v.z + v.w;
  float s2 = v.x*v.x + v.y*v.y + v.z*v.z + v.w*v.w;
#pragma unroll
  for (int o = 32; o > 0; o >>= 1) { s1 += __shfl_down(s1, o); s2 += __shfl_down(s2, o); }
  __shared__ float r1[3], r2[3];
  const int lane = tid & 63, wv = tid >> 6;
  if (lane == 0) { r1[wv] = s1; r2[wv] = s2; }
  __syncthreads();
  s1 = r1[0] + r1[1] + r1[2];
  s2 = r2[0] + r2[1] + r2[2];
  const float mu = s1 * (1.f / CDIM);
  const float rs = rsqrtf(s2 * (1.f / CDIM) - mu * mu + 1e-6f);
  const float4 w4 = ((const float4*)w)[tid];
  const float4 b4 = ((const float4*)b)[tid];
  ushort4 o4;
  o4.x = f2bf((v.x - mu) * rs * w4.x + b4.x);
  o4.y = f2bf((v.y - mu) * rs * w4.y + b4.y);
  o4.z = f2bf((v.z - mu) * rs * w4.z + b4.z);
  o4.w = f2bf((v.w - mu) * rs * w4.w + b4.w);
  ((ushort4*)(y + (size_t)row * CDIM))[tid] = o4;
}

// ---------------- bf16 GEMM: C[M][N] = A[M][K] * Wt[N][K]^T + bias ---------
// 128x128 tile, 4 waves (2x2), 16x16x32 MFMA, BK=32, double-buffered LDS,
// global_load_lds width-16 staging (m97 structure).
// MODE 0: store bf16.  MODE 1: store f32.  MODE 2: f32, out = resid + gamma*(acc+bias)
template<int MODE>
__global__ __launch_bounds__(256) void gemm_bt(
    const ushort* __restrict__ A, const ushort* __restrict__ Wt,
    const float* __restrict__ bias, void* __restrict__ Cout,
    int M, int N, int K, int nTN,
    const float* __restrict__ resid, const float* __restrict__ gammav)
{
  const int mt = blockIdx.x / nTN;
  const int nt = blockIdx.x - mt * nTN;
  const int m0 = mt * 128, n0 = nt * 128;
  const int tid  = threadIdx.x;
  const int lane = tid & 63, wid = tid >> 6;
  const int wm = wid >> 1, wn = wid & 1;          // 2x2 wave grid, 64x64 each
  const int lr = lane & 15, lk = lane >> 4;

  __shared__ __align__(16) ushort lds[2][8192];   // per buf: A[128][32] + B[128][32]

  f32x4 acc[4][4] = {};

  auto stage = [&](int kt, int buf) {
    const int k0 = kt * 32;
#pragma unroll
    for (int it = 0; it < 2; ++it) {
      const int c   = it * 256 + wid * 64 + lane;     // 16B chunk id, 512 total
      const int row = c >> 2, g = c & 3;
      const ushort* srcA = A + (size_t)(m0 + row) * K + (k0 + g * 8);
      ushort* dstA = &lds[buf][(it * 256 + wid * 64) * 8];   // wave-uniform base
      __builtin_amdgcn_global_load_lds(
          (const __attribute__((address_space(1))) uint32_t*)srcA,
          (__attribute__((address_space(3))) uint32_t*)dstA, 16, 0, 0);
      const ushort* srcB = Wt + (size_t)(n0 + row) * K + (k0 + g * 8);
      ushort* dstB = &lds[buf][4096 + (it * 256 + wid * 64) * 8];
      __builtin_amdgcn_global_load_lds(
          (const __attribute__((address_space(1))) uint32_t*)srcB,
          (__attribute__((address_space(3))) uint32_t*)dstB, 16, 0, 0);
    }
  };

  stage(0, 0);
  __syncthreads();
  const int nk = K >> 5;
  for (int kt = 0; kt < nk; ++kt) {
    const int cur = kt & 1;
    if (kt + 1 < nk) stage(kt + 1, cur ^ 1);
    const ushort* As = &lds[cur][0];
    const ushort* Bs = &lds[cur][4096];
    bfx8 af[4], bv[4];
#pragma unroll
    for (int m = 0; m < 4; ++m)
      af[m] = *(const bfx8*)(As + (wm * 64 + m * 16 + lr) * 32 + lk * 8);
#pragma unroll
    for (int n = 0; n < 4; ++n)
      bv[n] = *(const bfx8*)(Bs + (wn * 64 + n * 16 + lr) * 32 + lk * 8);
#pragma unroll
    for (int m = 0; m < 4; ++m)
#pragma unroll
      for (int n = 0; n < 4; ++n)
        acc[m][n] = __builtin_amdgcn_mfma_f32_16x16x32_bf16(af[m], bv[n], acc[m][n], 0, 0, 0);
    __syncthreads();
  }

  // epilogue: D row = 4*(lane>>4)+i, col = lane&15  (m89-verified layout)
#pragma unroll
  for (int n = 0; n < 4; ++n) {
    const int col = n0 + wn * 64 + n * 16 + lr;
    const float bcol = bias[col];
    float gcol = 0.f;
    if constexpr (MODE == 2) gcol = gammav[col];
#pragma unroll
    for (int m = 0; m < 4; ++m) {
      const int rbase = m0 + wm * 64 + m * 16 + lk * 4;
#pragma unroll
      for (int i = 0; i < 4; ++i) {
        const size_t o = (size_t)(rbase + i) * N + col;
        const float v = acc[m][n][i] + bcol;
        if constexpr (MODE == 0)      ((ushort*)Cout)[o] = f2bf(v);
        else if constexpr (MODE == 1) ((float*)Cout)[o]  = v;
        else                          ((float*)Cout)[o]  = resid[o] + gcol * v;
      }
    }
  }
}

// ---------------- softmax over 12 + pack sampling params --------------------
// one thread per (nq, h). Emits 12 x float4 {px, py, a, 0} per task.
__global__ void softmax_pack(const float* __restrict__ aw_raw,
                             const float* __restrict__ off_raw,
                             const float* __restrict__ refp,
                             float4* __restrict__ params) {
  const int t = blockIdx.x * 256 + threadIdx.x;       // [0, MQ*NHD)
  const int h = t % NHD, nq = t / NHD;
  const float* p = aw_raw + (size_t)nq * AW_NPAD + h * 12;
  float v[12], m = -1e30f;
#pragma unroll
  for (int j = 0; j < 12; ++j) { v[j] = p[j]; m = fmaxf(m, v[j]); }
  float s = 0.f;
#pragma unroll
  for (int j = 0; j < 12; ++j) { v[j] = __expf(v[j] - m); s += v[j]; }
  const float inv = 1.f / s;
  const float* op = off_raw + (size_t)nq * SO_NPAD + h * 24;
  const float* rp = refp + (size_t)nq * (NLVL * 2);
  float4* out = params + (size_t)t * 12;
  const float Wf[3] = {128.f, 64.f, 32.f};
#pragma unroll
  for (int l = 0; l < NLVL; ++l) {
    const float rxw = rp[2 * l] * Wf[l] - 0.5f;
    const float ryw = rp[2 * l + 1] * Wf[l] - 0.5f;
#pragma unroll
    for (int pt = 0; pt < NPT; ++pt) {
      float4 o4;
      o4.x = rxw + op[(l * 4 + pt) * 2 + 0];
      o4.y = ryw + op[(l * 4 + pt) * 2 + 1];
      o4.z = v[l * 4 + pt] * inv;
      o4.w = 0.f;
      out[l * 4 + pt] = o4;
    }
  }
}

// ---------------- deformable bilinear sampling (4 heads / wave) -------------
// wave w -> (nq = w/3, head-group hg = w%3). lane: head = hg*4 + (lane>>4),
// channels = (lane&15)*4 .. +3 (uint2 = 4 bf16 per gather).
__device__ __forceinline__ void bacc(uint2 g, float wgt,
                                     float& a0, float& a1, float& a2, float& a3) {
  union { uint32_t u; float f; } c;
  c.u = g.x << 16;          a0 += c.f * wgt;
  c.u = g.x & 0xffff0000u;  a1 += c.f * wgt;
  c.u = g.y << 16;          a2 += c.f * wgt;
  c.u = g.y & 0xffff0000u;  a3 += c.f * wgt;
}

__global__ __launch_bounds__(256) void deform_sample4(
    const char* __restrict__ vbytes, const float4* __restrict__ params,
    ushort* __restrict__ samp)
{
  const int w    = blockIdx.x * 4 + (threadIdx.x >> 6);
  const int lane = threadIdx.x & 63;
  const int nq   = w / 3;                     // wave-uniform
  const int hg   = w - nq * 3;
  const int h    = hg * 4 + (lane >> 4);
  const int n    = nq >> 12;                  // Lq = 4096
  const uint32_t laneoff = ((uint32_t)h << 7) + (uint32_t)((lane & 15) << 3);
  const float4* __restrict__ pp = params + ((size_t)nq * NHD + h) * 12;
  const uint32_t nbase = (uint32_t)n * (uint32_t)(LIN * CDIM * 2);

  float acc0 = 0.f, acc1 = 0.f, acc2 = 0.f, acc3 = 0.f;

  const int      Wl[3]  = {128, 64, 32};
  const uint32_t STb[3] = {0u, 16384u * 1536u, 20480u * 1536u};

#pragma unroll
  for (int l = 0; l < NLVL; ++l) {
    const int W_ = Wl[l];
    const uint32_t base = nbase + STb[l] + laneoff;
#pragma unroll
    for (int p = 0; p < NPT; ++p) {
      const float4 pt = pp[l * 4 + p];
      const float fx = floorf(pt.x), fy = floorf(pt.y);
      const float tx = pt.x - fx,   ty = pt.y - fy;
      const int x0 = (int)fx, y0 = (int)fy;
      const int x1 = x0 + 1,  y1 = y0 + 1;
      // ok-mask folded into weights (unsigned compare covers <0 and >=W)
      const float wx0 = ((uint32_t)x0 < (uint32_t)W_) ? (1.f - tx) : 0.f;
      const float wx1 = ((uint32_t)x1 < (uint32_t)W_) ? tx : 0.f;
      const float wy0 = ((uint32_t)y0 < (uint32_t)W_) ? pt.z * (1.f - ty) : 0.f;
      const float wy1 = ((uint32_t)y1 < (uint32_t)W_) ? pt.z * ty : 0.f;
      const int xc0 = min(max(x0, 0), W_ - 1);
      const int xc1 = min(max(x1, 0), W_ - 1);
      const int yr0 = min(max(y0, 0), W_ - 1) * W_;
      const int yr1 = min(max(y1, 0), W_ - 1) * W_;
      const float w00 = wy0 * wx0, w01 = wy0 * wx1;
      const float w10 = wy1 * wx0, w11 = wy1 * wx1;
      const uint2 g00 = *(const uint2*)(vbytes + (base + (uint32_t)(yr0 + xc0) * 1536u));
      const uint2 g01 = *(const uint2*)(vbytes + (base + (uint32_t)(yr0 + xc1) * 1536u));
      const uint2 g10 = *(const uint2*)(vbytes + (base + (uint32_t)(yr1 + xc0) * 1536u));
      const uint2 g11 = *(const uint2*)(vbytes + (base + (uint32_t)(yr1 + xc1) * 1536u));
      bacc(g00, w00, acc0, acc1, acc2, acc3);
      bacc(g01, w01, acc0, acc1, acc2, acc3);
      bacc(g10, w10, acc0, acc1, acc2, acc3);
      bacc(g11, w11, acc0, acc1, acc2, acc3);
    }
  }

  ushort4 o;
  o.x = f2bf(acc0); o.y = f2bf(acc1); o.z = f2bf(acc2); o.w = f2bf(acc3);
  *(ushort4*)(samp + (size_t)nq * CDIM + h * HDIM + (lane & 15) * 4) = o;
}

// ---------------- host ------------------------------------------------------
extern "C" void kernel_launch(void* const* d_in, const int* in_sizes, int n_in,
                              void* d_out, int out_size, void* d_ws, size_t ws_size,
                              hipStream_t stream) {
  const float* query = (const float*)d_in[0];
  const float* refp  = (const float*)d_in[1];
  const float* feat  = (const float*)d_in[2];
  const float* qn_w  = (const float*)d_in[3];
  const float* qn_b  = (const float*)d_in[4];
  const float* fn_w  = (const float*)d_in[5];
  const float* fn_b  = (const float*)d_in[6];
  const float* gamma = (const float*)d_in[7];
  const float* so_w  = (const float*)d_in[8];
  const float* so_b  = (const float*)d_in[9];
  const float* aw_w  = (const float*)d_in[10];
  const float* aw_b  = (const float*)d_in[11];
  const float* vp_w  = (const float*)d_in[12];
  const float* vp_b  = (const float*)d_in[13];
  const float* op_w  = (const float*)d_in[14];
  const float* op_b  = (const float*)d_in[15];

  char* ws = (char*)d_ws;
  size_t off = 0;
  auto alloc = [&](size_t bytes) {
    char* p = ws + off;
    off = (off + bytes + 255) & ~(size_t)255;
    return p;
  };
  ushort* q_bf   = (ushort*)alloc((size_t)MQ * CDIM * 2);
  ushort* val_bf = (ushort*)alloc((size_t)MF * CDIM * 2);
  ushort* vp_wT  = (ushort*)alloc((size_t)CDIM * CDIM * 2);
  ushort* op_wT  = (ushort*)alloc((size_t)CDIM * CDIM * 2);
  ushort* so_wT  = (ushort*)alloc((size_t)SO_NPAD * CDIM * 2);
  ushort* aw_wT  = (ushort*)alloc((size_t)AW_NPAD * CDIM * 2);
  float*  so_bp  = (float*)alloc(SO_NPAD * 4);
  float*  aw_bp  = (float*)alloc(AW_NPAD * 4);

  // region R: f_bf (phase A) aliases the phase-B buffers (value GEMM is the
  // last consumer of f_bf; so/aw GEMMs run strictly after it on the stream)
  const size_t r = off;
  ushort* f_bf = (ushort*)(ws + r);
  const size_t f_end = r + (size_t)MF * CDIM * 2;
  size_t o2 = r;
  float*  off_raw = (float*)(ws + o2);  o2 += (size_t)MQ * SO_NPAD * 4;
  float*  aw_raw  = (float*)(ws + o2);  o2 += (size_t)MQ * AW_NPAD * 4;
  float4* params  = (float4*)(ws + o2); o2 += (size_t)MQ * NHD * 12 * 16;
  ushort* samp    = (ushort*)(ws + o2); o2 += (size_t)MQ * CDIM * 2;
  const size_t need = (f_end > o2) ? f_end : o2;
  if (ws_size < need) return;   // ~293 MB required

  // 1) weights -> bf16 transposed (+ padded biases)
  transpose_cast<<<(CDIM * CDIM + 255) / 256, 256, 0, stream>>>(vp_w, vp_wT, CDIM, CDIM, CDIM);
  transpose_cast<<<(CDIM * CDIM + 255) / 256, 256, 0, stream>>>(op_w, op_wT, CDIM, CDIM, CDIM);
  transpose_cast<<<(SO_NPAD * CDIM + 255) / 256, 256, 0, stream>>>(so_w, so_wT, CDIM, SO_N, SO_NPAD);
  transpose_cast<<<(AW_NPAD * CDIM + 255) / 256, 256, 0, stream>>>(aw_w, aw_wT, CDIM, AW_N, AW_NPAD);
  pad_bias<<<2, 256, 0, stream>>>(so_b, so_bp, SO_N, SO_NPAD);
  pad_bias<<<1, 256, 0, stream>>>(aw_b, aw_bp, AW_N, AW_NPAD);

  // 2) layernorms -> bf16
  ln_cast<<<MQ, 192, 0, stream>>>(query, qn_w, qn_b, q_bf);
  ln_cast<<<MF, 192, 0, stream>>>(feat, fn_w, fn_b, f_bf);

  // 3) value = LN(feat) @ vp_w + vp_b          (bf16 out)
  gemm_bt<0><<<(MF / 128) * (CDIM / 128), 256, 0, stream>>>(
      f_bf, vp_wT, vp_b, val_bf, MF, CDIM, CDIM, CDIM / 128, nullptr, nullptr);

  // 4) sampling offsets / attention weights    (f32 out, padded N)
  gemm_bt<1><<<(MQ / 128) * (SO_NPAD / 128), 256, 0, stream>>>(
      q_bf, so_wT, so_bp, off_raw, MQ, SO_NPAD, CDIM, SO_NPAD / 128, nullptr, nullptr);
  gemm_bt<1><<<(MQ / 128) * (AW_NPAD / 128), 256, 0, stream>>>(
      q_bf, aw_wT, aw_bp, aw_raw, MQ, AW_NPAD, CDIM, AW_NPAD / 128, nullptr, nullptr);

  // 5) softmax + pack {px,py,a} per (q,h,l,p)
  softmax_pack<<<(MQ * NHD) / 256, 256, 0, stream>>>(aw_raw, off_raw, refp, params);

  // 6) deformable sampling -> samp bf16 [MQ][768]   (4 heads per wave)
  deform_sample4<<<(MQ * 3) / 4, 256, 0, stream>>>((const char*)val_bf, params, samp);

  // 7) out = query + gamma * (samp @ op_w + op_b)
  gemm_bt<2><<<(MQ / 128) * (CDIM / 128), 256, 0, stream>>>(
      samp, op_wT, op_b, (float*)d_out, MQ, CDIM, CDIM, CDIM / 128, query, gamma);
}

// Round 3
// 491.933 us; speedup vs baseline: 1.2005x; 1.0526x over previous
//
#include <hip/hip_runtime.h>
#include <hip/hip_bf16.h>
#include <stdint.h>

// ---------------- problem constants (fixed by setup_inputs) ----------------
#define NHD   12        // heads
#define NPT   4         // points
#define CDIM  768
#define HDIM  64
#define NLVL  3
#define LQ    4096
#define NB    4
#define LIN   21504     // 128*128 + 64*64 + 32*32
#define MQ    (NB*LQ)   // 16384 query rows
#define MF    (NB*LIN)  // 86016 feat rows
#define SO_N    288
#define SO_NPAD 384
#define AW_N    144
#define AW_NPAD 256

typedef __bf16 bfx8 __attribute__((ext_vector_type(8)));
typedef float  f32x4 __attribute__((ext_vector_type(4)));

__device__ __forceinline__ ushort f2bf(float x) {
  union { float f; uint32_t u; } v; v.f = x;
  uint32_t r = v.u + 0x7fffu + ((v.u >> 16) & 1u);   // RNE
  return (ushort)(r >> 16);
}

// ---------------- weight transpose + cast:  Wt[n][k] = bf16(W[k][n]) -------
__global__ void transpose_cast(const float* __restrict__ W, ushort* __restrict__ Wt,
                               int K, int Nsrc, int Npad) {
  int t = blockIdx.x * 256 + threadIdx.x;
  if (t >= Npad * K) return;
  int n = t / K, k = t - n * K;
  Wt[t] = (n < Nsrc) ? f2bf(W[(size_t)k * Nsrc + n]) : (ushort)0;
}

__global__ void pad_bias(const float* __restrict__ src, float* __restrict__ dst,
                         int nReal, int nPad) {
  int i = blockIdx.x * 256 + threadIdx.x;
  if (i < nPad) dst[i] = (i < nReal) ? src[i] : 0.f;
}

// ---------------- LayerNorm + cast to bf16 (one block per row) -------------
__global__ __launch_bounds__(192) void ln_cast(const float* __restrict__ x,
                                               const float* __restrict__ w,
                                               const float* __restrict__ b,
                                               ushort* __restrict__ y) {
  const int row = blockIdx.x;
  const int tid = threadIdx.x;                  // 192 threads * float4 = 768
  const float4 v = ((const float4*)(x + (size_t)row * CDIM))[tid];
  float s1 = v.x + v.y + v.z + v.w;
  float s2 = v.x*v.x + v.y*v.y + v.z*v.z + v.w*v.w;
#pragma unroll
  for (int o = 32; o > 0; o >>= 1) { s1 += __shfl_down(s1, o); s2 += __shfl_down(s2, o); }
  __shared__ float r1[3], r2[3];
  const int lane = tid & 63, wv = tid >> 6;
  if (lane == 0) { r1[wv] = s1; r2[wv] = s2; }
  __syncthreads();
  s1 = r1[0] + r1[1] + r1[2];
  s2 = r2[0] + r2[1] + r2[2];
  const float mu = s1 * (1.f / CDIM);
  const float rs = rsqrtf(s2 * (1.f / CDIM) - mu * mu + 1e-6f);
  const float4 w4 = ((const float4*)w)[tid];
  const float4 b4 = ((const float4*)b)[tid];
  ushort4 o4;
  o4.x = f2bf((v.x - mu) * rs * w4.x + b4.x);
  o4.y = f2bf((v.y - mu) * rs * w4.y + b4.y);
  o4.z = f2bf((v.z - mu) * rs * w4.z + b4.z);
  o4.w = f2bf((v.w - mu) * rs * w4.w + b4.w);
  ((ushort4*)(y + (size_t)row * CDIM))[tid] = o4;
}

// ---------------- bf16 GEMM: C[M][N] = A[M][K] * Wt[N][K]^T + bias ---------
// 128x128 tile, 4 waves (2x2), 16x16x32 MFMA, BK=32, double-buffered LDS,
// global_load_lds width-16 staging (m97 structure) + XCD-chunked swizzle so
// the nTN blocks sharing an A-panel land on the SAME XCD's L2.
// MODE 0: store bf16.  MODE 1: store f32.  MODE 2: f32, out = resid + gamma*(acc+bias)
template<int MODE>
__global__ __launch_bounds__(256) void gemm_bt(
    const ushort* __restrict__ A, const ushort* __restrict__ Wt,
    const float* __restrict__ bias, void* __restrict__ Cout,
    int M, int N, int K, int nTN,
    const float* __restrict__ resid, const float* __restrict__ gammav)
{
  int bid = blockIdx.x;
  const int nwg = gridDim.x;
  if ((nwg & 7) == 0) {                 // all our grids are %8==0 (bijective)
    const int chunk = nwg >> 3;
    bid = (bid & 7) * chunk + (bid >> 3);
  }
  const int mt = bid / nTN;
  const int nt = bid - mt * nTN;
  const int m0 = mt * 128, n0 = nt * 128;
  const int tid  = threadIdx.x;
  const int lane = tid & 63, wid = tid >> 6;
  const int wm = wid >> 1, wn = wid & 1;          // 2x2 wave grid, 64x64 each
  const int lr = lane & 15, lk = lane >> 4;

  __shared__ __align__(16) ushort lds[2][8192];   // per buf: A[128][32] + B[128][32]

  f32x4 acc[4][4] = {};

  auto stage = [&](int kt, int buf) {
    const int k0 = kt * 32;
#pragma unroll
    for (int it = 0; it < 2; ++it) {
      const int c   = it * 256 + wid * 64 + lane;     // 16B chunk id, 512 total
      const int row = c >> 2, g = c & 3;
      const ushort* srcA = A + (size_t)(m0 + row) * K + (k0 + g * 8);
      ushort* dstA = &lds[buf][(it * 256 + wid * 64) * 8];   // wave-uniform base
      __builtin_amdgcn_global_load_lds(
          (const __attribute__((address_space(1))) uint32_t*)srcA,
          (__attribute__((address_space(3))) uint32_t*)dstA, 16, 0, 0);
      const ushort* srcB = Wt + (size_t)(n0 + row) * K + (k0 + g * 8);
      ushort* dstB = &lds[buf][4096 + (it * 256 + wid * 64) * 8];
      __builtin_amdgcn_global_load_lds(
          (const __attribute__((address_space(1))) uint32_t*)srcB,
          (__attribute__((address_space(3))) uint32_t*)dstB, 16, 0, 0);
    }
  };

  stage(0, 0);
  __syncthreads();
  const int nk = K >> 5;
  for (int kt = 0; kt < nk; ++kt) {
    const int cur = kt & 1;
    if (kt + 1 < nk) stage(kt + 1, cur ^ 1);
    const ushort* As = &lds[cur][0];
    const ushort* Bs = &lds[cur][4096];
    bfx8 af[4], bv[4];
#pragma unroll
    for (int m = 0; m < 4; ++m)
      af[m] = *(const bfx8*)(As + (wm * 64 + m * 16 + lr) * 32 + lk * 8);
#pragma unroll
    for (int n = 0; n < 4; ++n)
      bv[n] = *(const bfx8*)(Bs + (wn * 64 + n * 16 + lr) * 32 + lk * 8);
#pragma unroll
    for (int m = 0; m < 4; ++m)
#pragma unroll
      for (int n = 0; n < 4; ++n)
        acc[m][n] = __builtin_amdgcn_mfma_f32_16x16x32_bf16(af[m], bv[n], acc[m][n], 0, 0, 0);
    __syncthreads();
  }

  // epilogue: D row = 4*(lane>>4)+i, col = lane&15  (m89-verified layout)
#pragma unroll
  for (int n = 0; n < 4; ++n) {
    const int col = n0 + wn * 64 + n * 16 + lr;
    const float bcol = bias[col];
    float gcol = 0.f;
    if constexpr (MODE == 2) gcol = gammav[col];
#pragma unroll
    for (int m = 0; m < 4; ++m) {
      const int rbase = m0 + wm * 64 + m * 16 + lk * 4;
#pragma unroll
      for (int i = 0; i < 4; ++i) {
        const size_t o = (size_t)(rbase + i) * N + col;
        const float v = acc[m][n][i] + bcol;
        if constexpr (MODE == 0)      ((ushort*)Cout)[o] = f2bf(v);
        else if constexpr (MODE == 1) ((float*)Cout)[o]  = v;
        else                          ((float*)Cout)[o]  = resid[o] + gcol * v;
      }
    }
  }
}

// ---------------- softmax over 12 + pack sampling params --------------------
// one thread per (nq, h). Emits 12 x float4 {px, py, a, 0} per task.
__global__ void softmax_pack(const float* __restrict__ aw_raw,
                             const float* __restrict__ off_raw,
                             const float* __restrict__ refp,
                             float4* __restrict__ params) {
  const int t = blockIdx.x * 256 + threadIdx.x;       // [0, MQ*NHD)
  const int h = t % NHD, nq = t / NHD;
  const float* p = aw_raw + (size_t)nq * AW_NPAD + h * 12;
  float v[12], m = -1e30f;
#pragma unroll
  for (int j = 0; j < 12; ++j) { v[j] = p[j]; m = fmaxf(m, v[j]); }
  float s = 0.f;
#pragma unroll
  for (int j = 0; j < 12; ++j) { v[j] = __expf(v[j] - m); s += v[j]; }
  const float inv = 1.f / s;
  const float* op = off_raw + (size_t)nq * SO_NPAD + h * 24;
  const float* rp = refp + (size_t)nq * (NLVL * 2);
  float4* out = params + (size_t)t * 12;
  const float Wf[3] = {128.f, 64.f, 32.f};
#pragma unroll
  for (int l = 0; l < NLVL; ++l) {
    const float rxw = rp[2 * l] * Wf[l] - 0.5f;
    const float ryw = rp[2 * l + 1] * Wf[l] - 0.5f;
#pragma unroll
    for (int pt = 0; pt < NPT; ++pt) {
      float4 o4;
      o4.x = rxw + op[(l * 4 + pt) * 2 + 0];
      o4.y = ryw + op[(l * 4 + pt) * 2 + 1];
      o4.z = v[l * 4 + pt] * inv;
      o4.w = 0.f;
      out[l * 4 + pt] = o4;
    }
  }
}

// ---------------- deformable bilinear sampling (4 heads / wave) -------------
// wave w -> (nq = w/3, head-group hg = w%3). lane: head = hg*4 + (lane>>4),
// channels = (lane&15)*4 .. +3 (uint2 = 4 bf16 per gather).
__device__ __forceinline__ void bacc(uint2 g, float wgt,
                                     float& a0, float& a1, float& a2, float& a3) {
  union { uint32_t u; float f; } c;
  c.u = g.x << 16;          a0 += c.f * wgt;
  c.u = g.x & 0xffff0000u;  a1 += c.f * wgt;
  c.u = g.y << 16;          a2 += c.f * wgt;
  c.u = g.y & 0xffff0000u;  a3 += c.f * wgt;
}

__global__ __launch_bounds__(256) void deform_sample4(
    const char* __restrict__ vbytes, const float4* __restrict__ params,
    ushort* __restrict__ samp)
{
  const int w    = blockIdx.x * 4 + (threadIdx.x >> 6);
  const int lane = threadIdx.x & 63;
  const int nq   = w / 3;                     // wave-uniform
  const int hg   = w - nq * 3;
  const int h    = hg * 4 + (lane >> 4);
  const int n    = nq >> 12;                  // Lq = 4096
  const uint32_t laneoff = ((uint32_t)h << 7) + (uint32_t)((lane & 15) << 3);
  const float4* __restrict__ pp = params + ((size_t)nq * NHD + h) * 12;
  const uint32_t nbase = (uint32_t)n * (uint32_t)(LIN * CDIM * 2);

  float acc0 = 0.f, acc1 = 0.f, acc2 = 0.f, acc3 = 0.f;

  const int      Wl[3]  = {128, 64, 32};
  const uint32_t STb[3] = {0u, 16384u * 1536u, 20480u * 1536u};

#pragma unroll
  for (int l = 0; l < NLVL; ++l) {
    const int W_ = Wl[l];
    const uint32_t base = nbase + STb[l] + laneoff;
#pragma unroll
    for (int p = 0; p < NPT; ++p) {
      const float4 pt = pp[l * 4 + p];
      const float fx = floorf(pt.x), fy = floorf(pt.y);
      const float tx = pt.x - fx,   ty = pt.y - fy;
      const int x0 = (int)fx, y0 = (int)fy;
      const int x1 = x0 + 1,  y1 = y0 + 1;
      // ok-mask folded into weights (unsigned compare covers <0 and >=W)
      const float wx0 = ((uint32_t)x0 < (uint32_t)W_) ? (1.f - tx) : 0.f;
      const float wx1 = ((uint32_t)x1 < (uint32_t)W_) ? tx : 0.f;
      const float wy0 = ((uint32_t)y0 < (uint32_t)W_) ? pt.z * (1.f - ty) : 0.f;
      const float wy1 = ((uint32_t)y1 < (uint32_t)W_) ? pt.z * ty : 0.f;
      const int xc0 = min(max(x0, 0), W_ - 1);
      const int xc1 = min(max(x1, 0), W_ - 1);
      const int yr0 = min(max(y0, 0), W_ - 1) * W_;
      const int yr1 = min(max(y1, 0), W_ - 1) * W_;
      const float w00 = wy0 * wx0, w01 = wy0 * wx1;
      const float w10 = wy1 * wx0, w11 = wy1 * wx1;
      const uint2 g00 = *(const uint2*)(vbytes + (base + (uint32_t)(yr0 + xc0) * 1536u));
      const uint2 g01 = *(const uint2*)(vbytes + (base + (uint32_t)(yr0 + xc1) * 1536u));
      const uint2 g10 = *(const uint2*)(vbytes + (base + (uint32_t)(yr1 + xc0) * 1536u));
      const uint2 g11 = *(const uint2*)(vbytes + (base + (uint32_t)(yr1 + xc1) * 1536u));
      bacc(g00, w00, acc0, acc1, acc2, acc3);
      bacc(g01, w01, acc0, acc1, acc2, acc3);
      bacc(g10, w10, acc0, acc1, acc2, acc3);
      bacc(g11, w11, acc0, acc1, acc2, acc3);
    }
  }

  ushort4 o;
  o.x = f2bf(acc0); o.y = f2bf(acc1); o.z = f2bf(acc2); o.w = f2bf(acc3);
  *(ushort4*)(samp + (size_t)nq * CDIM + h * HDIM + (lane & 15) * 4) = o;
}

// ---------------- host ------------------------------------------------------
extern "C" void kernel_launch(void* const* d_in, const int* in_sizes, int n_in,
                              void* d_out, int out_size, void* d_ws, size_t ws_size,
                              hipStream_t stream) {
  const float* query = (const float*)d_in[0];
  const float* refp  = (const float*)d_in[1];
  const float* feat  = (const float*)d_in[2];
  const float* qn_w  = (const float*)d_in[3];
  const float* qn_b  = (const float*)d_in[4];
  const float* fn_w  = (const float*)d_in[5];
  const float* fn_b  = (const float*)d_in[6];
  const float* gamma = (const float*)d_in[7];
  const float* so_w  = (const float*)d_in[8];
  const float* so_b  = (const float*)d_in[9];
  const float* aw_w  = (const float*)d_in[10];
  const float* aw_b  = (const float*)d_in[11];
  const float* vp_w  = (const float*)d_in[12];
  const float* vp_b  = (const float*)d_in[13];
  const float* op_w  = (const float*)d_in[14];
  const float* op_b  = (const float*)d_in[15];

  char* ws = (char*)d_ws;
  size_t off = 0;
  auto alloc = [&](size_t bytes) {
    char* p = ws + off;
    off = (off + bytes + 255) & ~(size_t)255;
    return p;
  };
  ushort* q_bf   = (ushort*)alloc((size_t)MQ * CDIM * 2);
  ushort* val_bf = (ushort*)alloc((size_t)MF * CDIM * 2);
  ushort* vp_wT  = (ushort*)alloc((size_t)CDIM * CDIM * 2);
  ushort* op_wT  = (ushort*)alloc((size_t)CDIM * CDIM * 2);
  ushort* so_wT  = (ushort*)alloc((size_t)SO_NPAD * CDIM * 2);
  ushort* aw_wT  = (ushort*)alloc((size_t)AW_NPAD * CDIM * 2);
  float*  so_bp  = (float*)alloc(SO_NPAD * 4);
  float*  aw_bp  = (float*)alloc(AW_NPAD * 4);

  // region R: f_bf (phase A) aliases the phase-B buffers (value GEMM is the
  // last consumer of f_bf; so/aw GEMMs run strictly after it on the stream)
  const size_t r = off;
  ushort* f_bf = (ushort*)(ws + r);
  const size_t f_end = r + (size_t)MF * CDIM * 2;
  size_t o2 = r;
  float*  off_raw = (float*)(ws + o2);  o2 += (size_t)MQ * SO_NPAD * 4;
  float*  aw_raw  = (float*)(ws + o2);  o2 += (size_t)MQ * AW_NPAD * 4;
  float4* params  = (float4*)(ws + o2); o2 += (size_t)MQ * NHD * 12 * 16;
  ushort* samp    = (ushort*)(ws + o2); o2 += (size_t)MQ * CDIM * 2;
  const size_t need = (f_end > o2) ? f_end : o2;
  if (ws_size < need) return;   // ~293 MB required

  // 1) weights -> bf16 transposed (+ padded biases)
  transpose_cast<<<(CDIM * CDIM + 255) / 256, 256, 0, stream>>>(vp_w, vp_wT, CDIM, CDIM, CDIM);
  transpose_cast<<<(CDIM * CDIM + 255) / 256, 256, 0, stream>>>(op_w, op_wT, CDIM, CDIM, CDIM);
  transpose_cast<<<(SO_NPAD * CDIM + 255) / 256, 256, 0, stream>>>(so_w, so_wT, CDIM, SO_N, SO_NPAD);
  transpose_cast<<<(AW_NPAD * CDIM + 255) / 256, 256, 0, stream>>>(aw_w, aw_wT, CDIM, AW_N, AW_NPAD);
  pad_bias<<<2, 256, 0, stream>>>(so_b, so_bp, SO_N, SO_NPAD);
  pad_bias<<<1, 256, 0, stream>>>(aw_b, aw_bp, AW_N, AW_NPAD);

  // 2) layernorms -> bf16
  ln_cast<<<MQ, 192, 0, stream>>>(query, qn_w, qn_b, q_bf);
  ln_cast<<<MF, 192, 0, stream>>>(feat, fn_w, fn_b, f_bf);

  // 3) value = LN(feat) @ vp_w + vp_b          (bf16 out)
  gemm_bt<0><<<(MF / 128) * (CDIM / 128), 256, 0, stream>>>(
      f_bf, vp_wT, vp_b, val_bf, MF, CDIM, CDIM, CDIM / 128, nullptr, nullptr);

  // 4) sampling offsets / attention weights    (f32 out, padded N)
  gemm_bt<1><<<(MQ / 128) * (SO_NPAD / 128), 256, 0, stream>>>(
      q_bf, so_wT, so_bp, off_raw, MQ, SO_NPAD, CDIM, SO_NPAD / 128, nullptr, nullptr);
  gemm_bt<1><<<(MQ / 128) * (AW_NPAD / 128), 256, 0, stream>>>(
      q_bf, aw_wT, aw_bp, aw_raw, MQ, AW_NPAD, CDIM, AW_NPAD / 128, nullptr, nullptr);

  // 5) softmax + pack {px,py,a} per (q,h,l,p)
  softmax_pack<<<(MQ * NHD) / 256, 256, 0, stream>>>(aw_raw, off_raw, refp, params);

  // 6) deformable sampling -> samp bf16 [MQ][768]   (4 heads per wave)
  deform_sample4<<<(MQ * 3) / 4, 256, 0, stream>>>((const char*)val_bf, params, samp);

  // 7) out = query + gamma * (samp @ op_w + op_b)
  gemm_bt<2><<<(MQ / 128) * (CDIM / 128), 256, 0, stream>>>(
      samp, op_wT, op_b, (float*)d_out, MQ, CDIM, CDIM, CDIM / 128, query, gamma);
}